// Round 4
// baseline (381.565 us; speedup 1.0000x reference)
//
#include <hip/hip_runtime.h>
#include <math.h>

#define NTOK 65536
#define DIMD 128
#define KCB  2048

typedef unsigned short u16;
typedef __attribute__((ext_vector_type(8))) unsigned short u16x8;
typedef __attribute__((ext_vector_type(8))) __bf16 bf16x8;
typedef __attribute__((ext_vector_type(4))) float f32x4;

union U8 { u16x8 u; bf16x8 b; };

__device__ __forceinline__ u16 f2bf(float f) {
  union { float f; unsigned u; } c; c.f = f;
  unsigned r = c.u + 0x7FFFu + ((c.u >> 16) & 1u);
  return (u16)(r >> 16);
}
__device__ __forceinline__ float bf2f(u16 h) {
  union { unsigned u; float f; } c; c.u = ((unsigned)h) << 16;
  return c.f;
}

__device__ __forceinline__ float block_reduce4(float v, volatile float* sm, int tid) {
  #pragma unroll
  for (int off = 32; off; off >>= 1) v += __shfl_xor(v, off, 64);
  __syncthreads();
  if ((tid & 63) == 0) sm[tid >> 6] = v;
  __syncthreads();
  float r = sm[0] + sm[1] + sm[2] + sm[3];
  __syncthreads();
  return r;
}

// issue 8 global_load_lds (16B) staging one 64-code half (H+L) -- vmcnt +8
__device__ __forceinline__ void stage_half(const char* srcH, const char* srcL, char* ldsBase) {
  #pragma unroll
  for (int i = 0; i < 4; ++i) {
    __builtin_amdgcn_global_load_lds((const __attribute__((address_space(1))) void*)(srcH + i * 4096),
                                     (__attribute__((address_space(3))) void*)(ldsBase + i * 4096), 16, 0, 0);
    __builtin_amdgcn_global_load_lds((const __attribute__((address_space(1))) void*)(srcL + i * 4096),
                                     (__attribute__((address_space(3))) void*)(ldsBase + 16384 + i * 4096), 16, 0, 0);
  }
}

// ---------------- small kernels ----------------

__global__ __launch_bounds__(256) void k_zero(float* __restrict__ avgp, float* __restrict__ t1,
                                              float* __restrict__ acc3, float* __restrict__ cnt) {
  const int i = blockIdx.x * 256 + threadIdx.x;
  if (i < KCB) { avgp[i] = 0.0f; cnt[i] = 0.0f; }
  if (i == 0) { t1[0] = 0.0f; acc3[0] = 0.0f; acc3[1] = 0.0f; acc3[2] = 0.0f; }
}

__global__ __launch_bounds__(256) void k_prepx(const float* __restrict__ x, const float* __restrict__ mask,
                                               float* __restrict__ scaleInv, u16* __restrict__ xh,
                                               u16* __restrict__ xl) {
  const int wid = (blockIdx.x * 256 + threadIdx.x) >> 6;
  const int lane = threadIdx.x & 63;
  if (wid >= NTOK) return;
  const float add = (1.0f - mask[wid]) * 1e-6f;
  const float2 v = *(const float2*)(x + (size_t)wid * DIMD + lane * 2);
  const float a0 = v.x + add, a1 = v.y + add;
  float ss = a0 * a0 + a1 * a1;
  #pragma unroll
  for (int off = 32; off; off >>= 1) ss += __shfl_xor(ss, off, 64);
  const float sc = 1.0f / fmaxf(sqrtf(ss), 1e-6f);
  if (lane == 0) scaleInv[wid] = sc;
  const float f0 = a0 * sc, f1 = a1 * sc;
  const u16 h0 = f2bf(f0), h1 = f2bf(f1);
  const u16 g0 = f2bf(f0 - bf2f(h0)), g1 = f2bf(f1 - bf2f(h1));
  union { u16 s[2]; unsigned u; } wh, wl;
  wh.s[0] = h0; wh.s[1] = h1; wl.s[0] = g0; wl.s[1] = g1;
  *(unsigned*)(xh + (size_t)wid * DIMD + lane * 2) = wh.u;
  *(unsigned*)(xl + (size_t)wid * DIMD + lane * 2) = wl.u;
}

__global__ __launch_bounds__(256) void k_splitcb(const float* __restrict__ cb, u16* __restrict__ cbh,
                                                 u16* __restrict__ cbl) {
  const int wid = (blockIdx.x * 256 + threadIdx.x) >> 6;
  const int lane = threadIdx.x & 63;
  if (wid >= KCB) return;
  const float2 v = *(const float2*)(cb + (size_t)wid * DIMD + lane * 2);
  const u16 h0 = f2bf(v.x), h1 = f2bf(v.y);
  const u16 g0 = f2bf(v.x - bf2f(h0)), g1 = f2bf(v.y - bf2f(h1));
  union { u16 s[2]; unsigned u; } wh, wl;
  wh.s[0] = h0; wh.s[1] = h1; wl.s[0] = g0; wl.s[1] = g1;
  *(unsigned*)(cbh + (size_t)wid * DIMD + lane * 2) = wh.u;
  *(unsigned*)(cbl + (size_t)wid * DIMD + lane * 2) = wl.u;
}

// refine (exact-f32 argmax for near-tie rows) fused with gather/count/enc.
// one wave per row; launch_bounds(256,1) so xr[32] stays in VGPRs (was spilling).
__global__ __launch_bounds__(256, 1) void k_refine(const float* __restrict__ x, const float* __restrict__ mask,
                                                   const float* __restrict__ cb, const float* __restrict__ scaleInv,
                                                   const float* __restrict__ rowV1, const float* __restrict__ rowV2,
                                                   const int* __restrict__ rowIdx, float* __restrict__ outQ,
                                                   float* __restrict__ outCnt, float* __restrict__ outEnc) {
  const int wid = (blockIdx.x * 256 + threadIdx.x) >> 6;
  const int lane = threadIdx.x & 63;
  if (wid >= NTOK) return;
  int idx;
  if (rowV1[wid] - rowV2[wid] > 1e-4f) {  // wave-uniform
    idx = rowIdx[wid];
  } else {
    const float add = (1.0f - mask[wid]) * 1e-6f;
    const float sc = scaleInv[wid];
    float4 xr[32];
    #pragma unroll
    for (int q = 0; q < 32; ++q) {
      const float4 t = *(const float4*)(x + (size_t)wid * DIMD + q * 4);
      xr[q].x = (t.x + add) * sc; xr[q].y = (t.y + add) * sc;
      xr[q].z = (t.z + add) * sc; xr[q].w = (t.w + add) * sc;
    }
    float best = -1e30f;
    int bidx = 0;
    for (int k = lane; k < KCB; k += 64) {
      const float4* crow = (const float4*)(cb + (size_t)k * DIMD);
      float d0 = 0.f, d1 = 0.f;
      #pragma unroll
      for (int q = 0; q < 32; q += 2) {
        const float4 c0 = crow[q];
        const float4 c1 = crow[q + 1];
        d0 = fmaf(c0.x, xr[q].x, d0);     d0 = fmaf(c0.y, xr[q].y, d0);
        d0 = fmaf(c0.z, xr[q].z, d0);     d0 = fmaf(c0.w, xr[q].w, d0);
        d1 = fmaf(c1.x, xr[q + 1].x, d1); d1 = fmaf(c1.y, xr[q + 1].y, d1);
        d1 = fmaf(c1.z, xr[q + 1].z, d1); d1 = fmaf(c1.w, xr[q + 1].w, d1);
      }
      const float d = d0 + d1;
      if (d > best) { best = d; bidx = k; }
    }
    #pragma unroll
    for (int off = 32; off; off >>= 1) {
      const float ob = __shfl_xor(best, off, 64);
      const int oi = __shfl_xor(bidx, off, 64);
      if (ob > best || (ob == best && oi < bidx)) { best = ob; bidx = oi; }
    }
    idx = bidx;  // all lanes converge to the same value
  }
  const float2 v = *(const float2*)(cb + (size_t)idx * DIMD + lane * 2);
  *(float2*)(outQ + (size_t)wid * DIMD + lane * 2) = v;
  if (lane == 0) {
    atomicAdd(&outCnt[idx], mask[wid]);
    outEnc[wid] = (float)idx;
  }
}

// ---------------- MFMA pass 1: per-row max / argmax(top2) / Z ----------------

__global__ __launch_bounds__(256, 2) void k_pass1(const u16* __restrict__ xh, const u16* __restrict__ xl,
                                                  const u16* __restrict__ cbh, const u16* __restrict__ cbl,
                                                  float* __restrict__ rowV1, float* __restrict__ rowZ,
                                                  float* __restrict__ rowV2, int* __restrict__ rowIdx) {
  __shared__ __align__(16) char Bsmem[65536];  // 2 half-buffers x (16KB H + 16KB L)
  const int tid = threadIdx.x;
  const int lane = tid & 63, w = tid >> 6;
  const int l15 = lane & 15, hi = lane >> 4;
  const int row0 = blockIdx.x * 128;

  const int tbase = ((tid >> 4) << 8) + ((((tid & 15) << 4)) ^ (((tid >> 4) & 7) << 4));
  const char* cbh_c = (const char*)cbh;
  const char* cbl_c = (const char*)cbl;

  U8 Ah[2][4], Al[2][4];
  #pragma unroll
  for (int mf = 0; mf < 2; ++mf) {
    const size_t arow = (size_t)(row0 + w * 32 + mf * 16 + l15);
    #pragma unroll
    for (int ks = 0; ks < 4; ++ks) {
      const size_t off = arow * DIMD + ks * 32 + hi * 8;
      Ah[mf][ks].u = *(const u16x8*)(xh + off);
      Al[mf][ks].u = *(const u16x8*)(xl + off);
    }
  }
  const int laneAB = l15 * 256;
  int koff[4];
  #pragma unroll
  for (int ks = 0; ks < 4; ++ks) koff[ks] = (ks * 64 + hi * 16) ^ ((l15 & 7) << 4);

  float v1[8], v2[8], rs[8];
  int k1[8];
  #pragma unroll
  for (int r = 0; r < 8; ++r) { v1[r] = -1e30f; v2[r] = -1e30f; rs[r] = 0.0f; k1[r] = 0; }

  stage_half(cbh_c + 0 * 16384 + tbase, cbl_c + 0 * 16384 + tbase, Bsmem + 0 * 32768 + w * 1024);
  stage_half(cbh_c + 1 * 16384 + tbase, cbl_c + 1 * 16384 + tbase, Bsmem + 1 * 32768 + w * 1024);

  #pragma unroll 2
  for (int t = 0; t < 32; ++t) {
    const int b = t & 1;
    if (t < 30) asm volatile("s_waitcnt vmcnt(8)" ::: "memory");
    else        asm volatile("s_waitcnt vmcnt(0)" ::: "memory");
    __builtin_amdgcn_sched_barrier(0);
    __builtin_amdgcn_s_barrier();
    __builtin_amdgcn_sched_barrier(0);

    const char* base = Bsmem + b * 32768;
    f32x4 acc[2][4];
    #pragma unroll
    for (int m = 0; m < 2; ++m)
      #pragma unroll
      for (int nf = 0; nf < 4; ++nf) acc[m][nf] = (f32x4){0.f, 0.f, 0.f, 0.f};

    __builtin_amdgcn_s_setprio(1);
    #pragma unroll
    for (int ks = 0; ks < 4; ++ks) {
      const char* pH = base + laneAB + koff[ks];
      const char* pL = pH + 16384;
      #pragma unroll
      for (int nf = 0; nf < 4; ++nf) {
        U8 bh, bl;
        bh.u = *(const u16x8*)(pH + nf * 4096);
        bl.u = *(const u16x8*)(pL + nf * 4096);
        acc[0][nf] = __builtin_amdgcn_mfma_f32_16x16x32_bf16(Ah[0][ks].b, bh.b, acc[0][nf], 0, 0, 0);
        acc[1][nf] = __builtin_amdgcn_mfma_f32_16x16x32_bf16(Ah[1][ks].b, bh.b, acc[1][nf], 0, 0, 0);
        acc[0][nf] = __builtin_amdgcn_mfma_f32_16x16x32_bf16(Al[0][ks].b, bh.b, acc[0][nf], 0, 0, 0);
        acc[1][nf] = __builtin_amdgcn_mfma_f32_16x16x32_bf16(Al[1][ks].b, bh.b, acc[1][nf], 0, 0, 0);
        acc[0][nf] = __builtin_amdgcn_mfma_f32_16x16x32_bf16(Ah[0][ks].b, bl.b, acc[0][nf], 0, 0, 0);
        acc[1][nf] = __builtin_amdgcn_mfma_f32_16x16x32_bf16(Ah[1][ks].b, bl.b, acc[1][nf], 0, 0, 0);
      }
    }
    __builtin_amdgcn_s_setprio(0);
    asm volatile("s_waitcnt lgkmcnt(0)" ::: "memory");
    __builtin_amdgcn_sched_barrier(0);
    __builtin_amdgcn_s_barrier();
    __builtin_amdgcn_sched_barrier(0);
    if (t < 30)
      stage_half(cbh_c + (size_t)(t + 2) * 16384 + tbase, cbl_c + (size_t)(t + 2) * 16384 + tbase,
                 Bsmem + b * 32768 + w * 1024);

    // epilogue (registers only) overlaps the prefetch
    const int colbase = t * 64 + l15;
    #pragma unroll
    for (int m = 0; m < 2; ++m)
      #pragma unroll
      for (int rg = 0; rg < 4; ++rg) {
        const int r = m * 4 + rg;
        float vv1 = v1[r], vv2 = v2[r];
        int kk1 = k1[r];
        const float mold = vv1;
        #pragma unroll
        for (int nf = 0; nf < 4; ++nf) {
          const float xv = acc[m][nf][rg];
          const int kk = colbase + nf * 16;
          const bool bb = xv > vv1;
          vv2 = bb ? vv1 : fmaxf(vv2, xv);
          kk1 = bb ? kk : kk1;
          vv1 = bb ? xv : vv1;
        }
        const float m200 = vv1 * 200.f;
        float z = rs[r] * __expf(fmaf(mold, 200.f, -m200));
        #pragma unroll
        for (int nf = 0; nf < 4; ++nf)
          z += __expf(fmaf(acc[m][nf][rg], 200.f, -m200));
        v1[r] = vv1; v2[r] = vv2; k1[r] = kk1; rs[r] = z;
      }
  }

  #pragma unroll
  for (int m = 0; m < 2; ++m)
    #pragma unroll
    for (int rg = 0; rg < 4; ++rg) {
      const int r = m * 4 + rg;
      float a1 = v1[r], a2 = v2[r], az = rs[r];
      int ak = k1[r];
      #pragma unroll
      for (int off = 1; off <= 8; off <<= 1) {
        const float o1 = __shfl_xor(a1, off, 64);
        const float o2 = __shfl_xor(a2, off, 64);
        const float oz = __shfl_xor(az, off, 64);
        const int okk = __shfl_xor(ak, off, 64);
        const float nm = fmaxf(a1, o1);
        az = az * __expf((a1 - nm) * 200.f) + oz * __expf((o1 - nm) * 200.f);
        a2 = fmaxf(fminf(a1, o1), fmaxf(a2, o2));
        const bool take = (o1 > a1) || (o1 == a1 && okk < ak);
        ak = take ? okk : ak;
        a1 = nm;
      }
      if (l15 == 0) {
        const int row = row0 + w * 32 + m * 16 + hi * 4 + rg;
        rowV1[row] = a1; rowZ[row] = az; rowV2[row] = a2; rowIdx[row] = ak;
      }
    }
}

// ---------------- MFMA pass 2: avg_probs column sums + sample-entropy ----------------

__global__ __launch_bounds__(256, 2) void k_pass2(const u16* __restrict__ xh, const u16* __restrict__ xl,
                                                  const u16* __restrict__ cbh, const u16* __restrict__ cbl,
                                                  const float* __restrict__ mask, const float* __restrict__ rowV1,
                                                  const float* __restrict__ rowZ, float* __restrict__ avgp,
                                                  float* __restrict__ t1g) {
  __shared__ __align__(16) char Bsmem[65536];
  __shared__ float ap[KCB];
  __shared__ float sm4[4];
  const int tid = threadIdx.x;
  const int lane = tid & 63, w = tid >> 6;
  const int l15 = lane & 15, hi = lane >> 4;
  const int row0 = blockIdx.x * 128;

  for (int i = tid; i < KCB; i += 256) ap[i] = 0.0f;

  const int tbase = ((tid >> 4) << 8) + ((((tid & 15) << 4)) ^ (((tid >> 4) & 7) << 4));
  const char* cbh_c = (const char*)cbh;
  const char* cbl_c = (const char*)cbl;

  U8 Ah[2][4], Al[2][4];
  #pragma unroll
  for (int mf = 0; mf < 2; ++mf) {
    const size_t arow = (size_t)(row0 + w * 32 + mf * 16 + l15);
    #pragma unroll
    for (int ks = 0; ks < 4; ++ks) {
      const size_t off = arow * DIMD + ks * 32 + hi * 8;
      Ah[mf][ks].u = *(const u16x8*)(xh + off);
      Al[mf][ks].u = *(const u16x8*)(xl + off);
    }
  }
  const int laneAB = l15 * 256;
  int koff[4];
  #pragma unroll
  for (int ks = 0; ks < 4; ++ks) koff[ks] = (ks * 64 + hi * 16) ^ ((l15 & 7) << 4);

  // offr = log(mask/Z) - 200*max  => p_masked = exp(200*s + offr); t1' = sum p*u'
  float offr[8];
  #pragma unroll
  for (int m = 0; m < 2; ++m)
    #pragma unroll
    for (int rg = 0; rg < 4; ++rg) {
      const int r = m * 4 + rg;
      const int row = row0 + w * 32 + m * 16 + hi * 4 + rg;
      const float zim = mask[row] / rowZ[row];
      const float lz = (zim > 0.0f) ? __logf(zim) : -1e30f;
      offr[r] = lz - 200.f * rowV1[row];
    }
  float t1 = 0.0f;

  stage_half(cbh_c + 0 * 16384 + tbase, cbl_c + 0 * 16384 + tbase, Bsmem + 0 * 32768 + w * 1024);
  stage_half(cbh_c + 1 * 16384 + tbase, cbl_c + 1 * 16384 + tbase, Bsmem + 1 * 32768 + w * 1024);

  // one barrier so the ap[] zeroing is visible before any wave's epilogue atomics
  __builtin_amdgcn_s_barrier();

  #pragma unroll 2
  for (int t = 0; t < 32; ++t) {
    const int b = t & 1;
    if (t < 30) asm volatile("s_waitcnt vmcnt(8)" ::: "memory");
    else        asm volatile("s_waitcnt vmcnt(0)" ::: "memory");
    __builtin_amdgcn_sched_barrier(0);
    __builtin_amdgcn_s_barrier();
    __builtin_amdgcn_sched_barrier(0);

    const char* base = Bsmem + b * 32768;
    f32x4 acc[2][4];
    #pragma unroll
    for (int m = 0; m < 2; ++m)
      #pragma unroll
      for (int nf = 0; nf < 4; ++nf) acc[m][nf] = (f32x4){0.f, 0.f, 0.f, 0.f};

    __builtin_amdgcn_s_setprio(1);
    #pragma unroll
    for (int ks = 0; ks < 4; ++ks) {
      const char* pH = base + laneAB + koff[ks];
      const char* pL = pH + 16384;
      #pragma unroll
      for (int nf = 0; nf < 4; ++nf) {
        U8 bh, bl;
        bh.u = *(const u16x8*)(pH + nf * 4096);
        bl.u = *(const u16x8*)(pL + nf * 4096);
        acc[0][nf] = __builtin_amdgcn_mfma_f32_16x16x32_bf16(Ah[0][ks].b, bh.b, acc[0][nf], 0, 0, 0);
        acc[1][nf] = __builtin_amdgcn_mfma_f32_16x16x32_bf16(Ah[1][ks].b, bh.b, acc[1][nf], 0, 0, 0);
        acc[0][nf] = __builtin_amdgcn_mfma_f32_16x16x32_bf16(Al[0][ks].b, bh.b, acc[0][nf], 0, 0, 0);
        acc[1][nf] = __builtin_amdgcn_mfma_f32_16x16x32_bf16(Al[1][ks].b, bh.b, acc[1][nf], 0, 0, 0);
        acc[0][nf] = __builtin_amdgcn_mfma_f32_16x16x32_bf16(Ah[0][ks].b, bl.b, acc[0][nf], 0, 0, 0);
        acc[1][nf] = __builtin_amdgcn_mfma_f32_16x16x32_bf16(Ah[1][ks].b, bl.b, acc[1][nf], 0, 0, 0);
      }
    }
    __builtin_amdgcn_s_setprio(0);
    asm volatile("s_waitcnt lgkmcnt(0)" ::: "memory");
    __builtin_amdgcn_sched_barrier(0);
    __builtin_amdgcn_s_barrier();
    __builtin_amdgcn_sched_barrier(0);
    if (t < 30)
      stage_half(cbh_c + (size_t)(t + 2) * 16384 + tbase, cbl_c + (size_t)(t + 2) * 16384 + tbase,
                 Bsmem + b * 32768 + w * 1024);

    float colsum[4];
    #pragma unroll
    for (int nf = 0; nf < 4; ++nf) colsum[nf] = 0.0f;
    #pragma unroll
    for (int m = 0; m < 2; ++m)
      #pragma unroll
      for (int rg = 0; rg < 4; ++rg) {
        const int r = m * 4 + rg;
        #pragma unroll
        for (int nf = 0; nf < 4; ++nf) {
          const float up = fmaf(acc[m][nf][rg], 200.f, offr[r]);
          const float p = __expf(up);
          colsum[nf] += p;
          t1 = fmaf(p, up, t1);
        }
      }
    #pragma unroll
    for (int nf = 0; nf < 4; ++nf) {
      colsum[nf] += __shfl_xor(colsum[nf], 16, 64);
      colsum[nf] += __shfl_xor(colsum[nf], 32, 64);
    }
    if (lane < 16) {
      #pragma unroll
      for (int nf = 0; nf < 4; ++nf)
        atomicAdd(&ap[t * 64 + nf * 16 + lane], colsum[nf]);
    }
  }

  __syncthreads();
  for (int i = tid; i < KCB; i += 256) atomicAdd(&avgp[i], ap[i]);
  #pragma unroll
  for (int off = 32; off; off >>= 1) t1 += __shfl_xor(t1, off, 64);
  if ((tid & 63) == 0) sm4[tid >> 6] = t1;
  __syncthreads();
  if (tid == 0) atomicAdd(t1g, sm4[0] + sm4[1] + sm4[2] + sm4[3]);
}

// ---------------- scalar reductions ----------------

__global__ __launch_bounds__(256) void k_stats(const float* __restrict__ mask, const float* __restrict__ rowV1,
                                               float* __restrict__ acc3) {
  __shared__ float sm[4];
  const int tid = threadIdx.x;
  float msum = 0.f, slat = 0.f;
  for (int n = blockIdx.x * 256 + tid; n < NTOK; n += gridDim.x * 256) {
    const float mk = mask[n];
    msum += mk;
    slat = fmaf(mk, 2.0f - 2.0f * rowV1[n], slat);
  }
  msum = block_reduce4(msum, sm, tid);
  slat = block_reduce4(slat, sm, tid);
  if (tid == 0) {
    atomicAdd(&acc3[0], msum);
    atomicAdd(&acc3[1], slat);
  }
}

__global__ __launch_bounds__(256) void k_final(const float* __restrict__ avgp, const float* __restrict__ t1g,
                                               const float* __restrict__ acc3, float* __restrict__ out3) {
  __shared__ float sm[4];
  const int tid = threadIdx.x;
  const float msum = acc3[0];
  float ae = 0.f;
  for (int k2 = tid; k2 < KCB; k2 += 256) {
    const float a = avgp[k2] / msum;
    ae += a * __logf(a + 1e-5f);
  }
  ae = block_reduce4(ae, sm, tid);
  if (tid == 0) {
    const float sample_entropy = -t1g[0] / msum;  // slogz folded analytically
    const float lat = acc3[1] / (msum + 1e-6f);
    out3[0] = lat;
    out3[1] = lat;
    out3[2] = sample_entropy + ae;
  }
}

// ---------------- launcher ----------------

extern "C" void kernel_launch(void* const* d_in, const int* in_sizes, int n_in,
                              void* d_out, int out_size, void* d_ws, size_t ws_size,
                              hipStream_t stream) {
  const float* x = (const float*)d_in[0];
  const float* mask = (const float*)d_in[1];
  const float* cb = (const float*)d_in[2];

  float* out = (float*)d_out;
  float* outQ = out;
  float* out3 = out + (size_t)NTOK * DIMD;
  float* outCnt = out3 + 3;
  float* outEnc = outCnt + KCB;

  // bf16-split x lives in the quantized output region until k_refine overwrites it
  u16* xh = (u16*)outQ;
  u16* xl = xh + (size_t)NTOK * DIMD;

  float* ws = (float*)d_ws;
  float* scaleInv = ws;                        // N
  float* rowV1 = ws + NTOK;                    // N
  float* rowZ = ws + 2 * (size_t)NTOK;         // N
  float* rowV2 = ws + 3 * (size_t)NTOK;        // N
  int* rowIdx = (int*)(ws + 4 * (size_t)NTOK); // N
  float* avgp = ws + 5 * (size_t)NTOK;         // K
  float* t1g = avgp + KCB;                     // 1
  float* acc3 = t1g + 1;                       // 3
  u16* cbh = (u16*)(ws + 5 * (size_t)NTOK + KCB + 8);
  u16* cbl = cbh + (size_t)KCB * DIMD;

  k_zero<<<(KCB + 255) / 256, 256, 0, stream>>>(avgp, t1g, acc3, outCnt);
  k_prepx<<<(NTOK * 64) / 256, 256, 0, stream>>>(x, mask, scaleInv, xh, xl);
  k_splitcb<<<(KCB * 64) / 256, 256, 0, stream>>>(cb, cbh, cbl);
  k_pass1<<<NTOK / 128, 256, 0, stream>>>(xh, xl, cbh, cbl, rowV1, rowZ, rowV2, rowIdx);
  k_pass2<<<NTOK / 128, 256, 0, stream>>>(xh, xl, cbh, cbl, mask, rowV1, rowZ, avgp, t1g);
  k_stats<<<64, 256, 0, stream>>>(mask, rowV1, acc3);
  // refine overwrites outQ (aliases xh/xl) -> must run after pass2
  k_refine<<<(NTOK * 64) / 256, 256, 0, stream>>>(x, mask, cb, scaleInv, rowV1, rowV2, rowIdx,
                                                  outQ, outCnt, outEnc);
  k_final<<<1, 256, 0, stream>>>(avgp, t1g, acc3, out3);
}